// Round 1
// 267.584 us; speedup vs baseline: 1.0049x; 1.0049x over previous
//
#include <hip/hip_runtime.h>

// Problem constants (from setup_inputs)
#define NB 8
#define NC 3
#define NT 32
#define NH 224
#define NW 224
#define DIFF 16
#define INV_SCALE (224.0f / 240.0f)   // in/out = 14/15

#define TILE_ROWS 16                  // output rows per block
#define LDS_ROWS 16                   // input rows staged (span of 16 out rows = <=16 in rows)
#define TILES_PER_FRAME (NH / TILE_ROWS)   // 14
#define NFRAMES (NB * NC * NT)        // 768

// One output COLUMN per thread, loop over the 16 tile rows.
// - LDS reads: consecutive lanes hit consecutive-or-equal words (stride 14/15)
//   -> <=2 lanes/bank, conflict-free (vs ~8-way in the quad-per-thread layout).
// - x-weights (ix, x0, fx) computed ONCE per thread instead of per pixel.
// - Stores: all lanes of a wave write one contiguous 256B row segment -> coalesced.
__global__ __launch_bounds__(256) void shake_crop_col_kernel(
    const float* __restrict__ video,
    const int* __restrict__ shake_h,
    const int* __restrict__ shake_w,
    float* __restrict__ out)
{
    __shared__ float lds[LDS_ROWS * NW];   // 14336 B -> 8 blocks/CU

    const int tid  = threadIdx.x;
    const int f    = blockIdx.x / TILES_PER_FRAME;   // frame index (b*C+c)*T + t
    const int tile = blockIdx.x % TILES_PER_FRAME;
    const int t    = f % NT;
    const int ybase = tile * TILE_ROWS;

    const int sh = shake_h[t];
    const int sw = shake_w[t];

    // Input-row span for output rows ybase..ybase+15 (iy monotone; span <= 16 rows)
    float iy_first = fminf(fmaxf((ybase + sh + 0.5f) * INV_SCALE - 0.5f, 0.0f), (float)(NH - 1));
    float iy_last  = fminf(fmaxf((ybase + TILE_ROWS - 1 + sh + 0.5f) * INV_SCALE - 0.5f, 0.0f), (float)(NH - 1));
    const int r0    = (int)iy_first;
    const int r_end = min((int)iy_last + 1, NH - 1);
    const int nrows = r_end - r0 + 1;                      // <= 16

    // Stage rows r0..r_end: one contiguous global span, coalesced float4 copy
    const float* frame = video + (size_t)f * (NH * NW);
    const float4* src4 = (const float4*)(frame + r0 * NW); // 224*4B rows stay 16B-aligned
    float4* lds4 = (float4*)lds;
    const int n4 = nrows * (NW / 4);                       // <= 896
    for (int j = tid; j < n4; j += 256)
        lds4[j] = src4[j];
    __syncthreads();

    const int x = tid;
    if (x >= NW) return;   // lanes 224..255 only helped stage (no more barriers below)

    // Per-column horizontal weights: computed once, reused for all 16 rows
    float ix = fminf(fmaxf((x + sw + 0.5f) * INV_SCALE - 0.5f, 0.0f), (float)(NW - 1));
    int   x0 = (int)ix;
    float fx = ix - (float)x0;
    int   x1 = min(x0 + 1, NW - 1);

    float* ocol = out + (size_t)f * (NH * NW) + (size_t)ybase * NW + x;

    #pragma unroll
    for (int ry = 0; ry < TILE_ROWS; ++ry) {
        float iy = fminf(fmaxf((ybase + ry + sh + 0.5f) * INV_SCALE - 0.5f, 0.0f), (float)(NH - 1));
        int   y0 = (int)iy;
        float fy = iy - (float)y0;
        int   y1 = min(y0 + 1, NH - 1);
        const float* row0 = lds + (y0 - r0) * NW;
        const float* row1 = lds + (y1 - r0) * NW;

        float v00 = row0[x0];
        float v01 = row0[x1];
        float v10 = row1[x0];
        float v11 = row1[x1];

        float top = v00 + fx * (v01 - v00);
        float bot = v10 + fx * (v11 - v10);
        float v   = top + fy * (bot - top);
        ocol[(size_t)ry * NW] = fminf(fmaxf(v, 0.0f), 1.0f);
    }
}

extern "C" void kernel_launch(void* const* d_in, const int* in_sizes, int n_in,
                              void* d_out, int out_size, void* d_ws, size_t ws_size,
                              hipStream_t stream) {
    const float* video   = (const float*)d_in[0];
    const int*   shake_h = (const int*)d_in[1];
    const int*   shake_w = (const int*)d_in[2];
    float*       out     = (float*)d_out;

    const int grid = NFRAMES * TILES_PER_FRAME;   // 10752 blocks
    shake_crop_col_kernel<<<grid, 256, 0, stream>>>(video, shake_h, shake_w, out);
}